// Round 6
// baseline (250.185 us; speedup 1.0000x reference)
//
#include <hip/hip_runtime.h>

#define DIM 128
#define NUM_OUT 100000
#define N_SRC 200000
#define OFFS_BYTES (((4 * (NUM_OUT + 1)) + 511) / 512 * 512)

typedef float v2f __attribute__((ext_vector_type(2)));
typedef float v4f __attribute__((ext_vector_type(4)));

__device__ __forceinline__ float fast_tanh(float x) {
  const float xc = fminf(fmaxf(x, -15.f), 15.f);
  const float t = __expf(2.f * xc);
  return __fdividef(t - 1.f, t + 1.f);
}

// Kernel 0: segment boundaries. offs[s] = first edge e with seg[e] >= s.
__global__ __launch_bounds__(256) void build_offs(
    const int* __restrict__ seg, int* __restrict__ offs, int n_edges, int n_out) {
  const int e = blockIdx.x * 256 + threadIdx.x;
  if (e >= n_edges) return;
  const int se = seg[e];
  int sp = __shfl_up(se, 1);
  if ((threadIdx.x & 63) == 0) sp = (e == 0) ? -1 : seg[e - 1];
  for (int s = sp + 1; s <= se; ++s) offs[s] = e;
  if (e == n_edges - 1) {
    for (int s = se + 1; s <= n_out; ++s) offs[s] = n_edges;
  }
}

// Kernel 1: per-segment gather+sum, 2-pass values-chunked for L3 residency.
// 128 threads = 2 waves = 2 segments/block. Pass c gathers only rows in
// values-chunk c (51 MB, L3-resident); other rows are clamped to a fixed
// in-chunk row (L1-hit) and masked out via fmaf. 8 gathers always in flight.
__global__ __launch_bounds__(128) void seg_gather_sum(
    const float* __restrict__ values,
    const int* __restrict__ gidx,
    const int* __restrict__ offs,
    float* __restrict__ g,
    int n_edges) {
  const int s = blockIdx.x * 2 + (threadIdx.x >> 6);
  const int t = threadIdx.x & 63;

  const int e0 = __builtin_amdgcn_readfirstlane(offs[s]);
  const int e1 = __builtin_amdgcn_readfirstlane(offs[s + 1]);
  const int len = e1 - e0;

  const v2f* __restrict__ v2 = (const v2f*)values;
  float accx = 0.f, accy = 0.f;

#pragma unroll 1
  for (int c = 0; c < 2; ++c) {
    const int clo = c * (N_SRC / 2);
    const int chi = clo + (N_SRC / 2);
#pragma unroll 1
    for (int base = 0; base < len; base += 64) {
      // one coalesced nt load covers up to 64 edge indices for this window
      const int my = __builtin_nontemporal_load(&gidx[min(e0 + base + t, n_edges - 1)]);
      const int n = min(64, len - base);
#pragma unroll 1
      for (int k = 0; k < n; k += 8) {
        const int nm1 = n - 1;
        int u[8];
        float m[8];
#pragma unroll
        for (int j = 0; j < 8; ++j) {
          const int kk = k + j;
          const int rj = __builtin_amdgcn_readlane(my, kk < nm1 ? kk : nm1);
          const bool inc = (rj >= clo) && (rj < chi);
          u[j] = inc ? rj : clo;
          m[j] = (inc && kk < n) ? 1.f : 0.f;
        }
        v2f a[8];
#pragma unroll
        for (int j = 0; j < 8; ++j) a[j] = v2[(size_t)u[j] * (DIM / 2) + t];
#pragma unroll
        for (int j = 0; j < 8; ++j) {
          accx = fmaf(m[j], a[j].x, accx);
          accy = fmaf(m[j], a[j].y, accy);
        }
      }
    }
  }

  v2f r;
  r.x = accx;
  r.y = accy;
  __builtin_nontemporal_store(r, &((v2f*)g)[(size_t)s * (DIM / 2) + t]);
}

// Kernel 2: out = tanh(g @ W). Register-tiled, no LDS (proven R2 form).
__global__ __launch_bounds__(256) void gemm_tanh(
    const float* __restrict__ g,
    const float* __restrict__ W,
    float* __restrict__ out,
    int n_rows) {
  const int lane = threadIdx.x & 63;
  const int wv = threadIdx.x >> 6;   // 0..3
  const int h = lane >> 5;           // 0..1
  const int tx = lane & 31;          // 0..31
  const int f = tx * 4;              // output col base
  const int r0 = blockIdx.x * 64 + wv * 16 + h * 8;

  const float* gp[8];
#pragma unroll
  for (int r = 0; r < 8; ++r) {
    int rr = r0 + r;
    rr = rr < n_rows ? rr : n_rows - 1;
    gp[r] = g + (size_t)rr * DIM;
  }

  float acc[8][4] = {};
#pragma unroll 2
  for (int d = 0; d < DIM; d += 2) {
    const v4f w0 = *(const v4f*)(W + (d + 0) * DIM + f);
    const v4f w1 = *(const v4f*)(W + (d + 1) * DIM + f);
#pragma unroll
    for (int r = 0; r < 8; ++r) {
      const v2f gv = *(const v2f*)(gp[r] + d);
      acc[r][0] = fmaf(gv.x, w0.x, acc[r][0]);
      acc[r][1] = fmaf(gv.x, w0.y, acc[r][1]);
      acc[r][2] = fmaf(gv.x, w0.z, acc[r][2]);
      acc[r][3] = fmaf(gv.x, w0.w, acc[r][3]);
      acc[r][0] = fmaf(gv.y, w1.x, acc[r][0]);
      acc[r][1] = fmaf(gv.y, w1.y, acc[r][1]);
      acc[r][2] = fmaf(gv.y, w1.z, acc[r][2]);
      acc[r][3] = fmaf(gv.y, w1.w, acc[r][3]);
    }
  }

#pragma unroll
  for (int r = 0; r < 8; ++r) {
    const int rr = r0 + r;
    if (rr < n_rows) {
      v4f o;
      o.x = fast_tanh(acc[r][0]);
      o.y = fast_tanh(acc[r][1]);
      o.z = fast_tanh(acc[r][2]);
      o.w = fast_tanh(acc[r][3]);
      *(v4f*)(out + (size_t)rr * DIM + f) = o;
    }
  }
}

extern "C" void kernel_launch(void* const* d_in, const int* in_sizes, int n_in,
                              void* d_out, int out_size, void* d_ws, size_t ws_size,
                              hipStream_t stream) {
  const float* values = (const float*)d_in[0];   // [N_SRC, 128] f32
  const float* W      = (const float*)d_in[1];   // [128, 128] f32
  const int*   gidx   = (const int*)d_in[2];     // [E] int
  const int*   seg    = (const int*)d_in[3];     // [E] int, sorted
  float* out = (float*)d_out;                    // [N_OUT, 128] f32

  int*   offs = (int*)d_ws;                          // [N_OUT+1]
  float* g    = (float*)((char*)d_ws + OFFS_BYTES);  // [N_OUT, 128] f32

  const int n_edges = in_sizes[2];

  build_offs<<<(n_edges + 255) / 256, 256, 0, stream>>>(seg, offs, n_edges, NUM_OUT);
  seg_gather_sum<<<NUM_OUT / 2, 128, 0, stream>>>(values, gidx, offs, g, n_edges);
  gemm_tanh<<<(NUM_OUT + 63) / 64, 256, 0, stream>>>(g, W, out, NUM_OUT);
}

// Round 7
// 210.816 us; speedup vs baseline: 1.1867x; 1.1867x over previous
//
#include <hip/hip_runtime.h>

#define DIM 128
#define NUM_OUT 100000
#define OFFS_BYTES (((4 * (NUM_OUT + 1)) + 511) / 512 * 512)

typedef float v2f __attribute__((ext_vector_type(2)));
typedef float v4f __attribute__((ext_vector_type(4)));

__device__ __forceinline__ float fast_tanh(float x) {
  const float xc = fminf(fmaxf(x, -15.f), 15.f);
  const float t = __expf(2.f * xc);
  return __fdividef(t - 1.f, t + 1.f);
}

// Kernel 0: segment boundaries. offs[s] = first edge e with seg[e] >= s.
__global__ __launch_bounds__(256) void build_offs(
    const int* __restrict__ seg, int* __restrict__ offs, int n_edges, int n_out) {
  const int e = blockIdx.x * 256 + threadIdx.x;
  if (e >= n_edges) return;
  const int se = seg[e];
  const int sp = (e == 0) ? -1 : seg[e - 1];
  for (int s = sp + 1; s <= se; ++s) offs[s] = e;
  if (e == n_edges - 1) {
    for (int s = se + 1; s <= n_out; ++s) offs[s] = n_edges;
  }
}

// Kernel 1: per-segment gather+sum. 128 threads = 2 waves = 2 segments/block.
// Edge indices loaded coalesced once per 64-edge window, broadcast to SGPRs
// via readlane. 16 gathers in flight per batch; tail lanes clamp to the last
// real row (L1-hit) and are masked out via fmaf — median segment (len~16) is
// a single batch, halving serial depth vs the 8-wide version.
__global__ __launch_bounds__(128) void seg_gather_sum(
    const float* __restrict__ values,
    const int* __restrict__ gidx,
    const int* __restrict__ offs,
    float* __restrict__ g,
    int n_edges) {
  const int s = blockIdx.x * 2 + (threadIdx.x >> 6);
  const int t = threadIdx.x & 63;

  const int e0 = __builtin_amdgcn_readfirstlane(offs[s]);
  const int e1 = __builtin_amdgcn_readfirstlane(offs[s + 1]);
  const int len = e1 - e0;

  const v2f* __restrict__ v2 = (const v2f*)values;
  float accx = 0.f, accy = 0.f;

#pragma unroll 1
  for (int base = 0; base < len; base += 64) {
    // one coalesced load covers up to 64 edge indices for this window
    const int my = gidx[min(e0 + base + t, n_edges - 1)];
    const int n = min(64, len - base);
    const int nm1 = n - 1;
#pragma unroll 1
    for (int k = 0; k < n; k += 16) {
      int u[16];
      float m[16];
#pragma unroll
      for (int j = 0; j < 16; ++j) {
        const int kk = k + j;
        u[j] = __builtin_amdgcn_readlane(my, kk < nm1 ? kk : nm1);
        m[j] = (kk < n) ? 1.f : 0.f;
      }
      v2f a[16];
#pragma unroll
      for (int j = 0; j < 16; ++j) a[j] = v2[(size_t)u[j] * (DIM / 2) + t];
#pragma unroll
      for (int j = 0; j < 16; ++j) {
        accx = fmaf(m[j], a[j].x, accx);
        accy = fmaf(m[j], a[j].y, accy);
      }
    }
  }

  v2f r;
  r.x = accx;
  r.y = accy;
  ((v2f*)g)[(size_t)s * (DIM / 2) + t] = r;
}

// Kernel 2: out = tanh(g @ W). Register-tiled, no LDS (proven R2 form).
__global__ __launch_bounds__(256) void gemm_tanh(
    const float* __restrict__ g,
    const float* __restrict__ W,
    float* __restrict__ out,
    int n_rows) {
  const int lane = threadIdx.x & 63;
  const int wv = threadIdx.x >> 6;   // 0..3
  const int h = lane >> 5;           // 0..1
  const int tx = lane & 31;          // 0..31
  const int f = tx * 4;              // output col base
  const int r0 = blockIdx.x * 64 + wv * 16 + h * 8;

  const float* gp[8];
#pragma unroll
  for (int r = 0; r < 8; ++r) {
    int rr = r0 + r;
    rr = rr < n_rows ? rr : n_rows - 1;
    gp[r] = g + (size_t)rr * DIM;
  }

  float acc[8][4] = {};
#pragma unroll 2
  for (int d = 0; d < DIM; d += 2) {
    const v4f w0 = *(const v4f*)(W + (d + 0) * DIM + f);
    const v4f w1 = *(const v4f*)(W + (d + 1) * DIM + f);
#pragma unroll
    for (int r = 0; r < 8; ++r) {
      const v2f gv = *(const v2f*)(gp[r] + d);
      acc[r][0] = fmaf(gv.x, w0.x, acc[r][0]);
      acc[r][1] = fmaf(gv.x, w0.y, acc[r][1]);
      acc[r][2] = fmaf(gv.x, w0.z, acc[r][2]);
      acc[r][3] = fmaf(gv.x, w0.w, acc[r][3]);
      acc[r][0] = fmaf(gv.y, w1.x, acc[r][0]);
      acc[r][1] = fmaf(gv.y, w1.y, acc[r][1]);
      acc[r][2] = fmaf(gv.y, w1.z, acc[r][2]);
      acc[r][3] = fmaf(gv.y, w1.w, acc[r][3]);
    }
  }

#pragma unroll
  for (int r = 0; r < 8; ++r) {
    const int rr = r0 + r;
    if (rr < n_rows) {
      v4f o;
      o.x = fast_tanh(acc[r][0]);
      o.y = fast_tanh(acc[r][1]);
      o.z = fast_tanh(acc[r][2]);
      o.w = fast_tanh(acc[r][3]);
      *(v4f*)(out + (size_t)rr * DIM + f) = o;
    }
  }
}

extern "C" void kernel_launch(void* const* d_in, const int* in_sizes, int n_in,
                              void* d_out, int out_size, void* d_ws, size_t ws_size,
                              hipStream_t stream) {
  const float* values = (const float*)d_in[0];   // [N_SRC, 128] f32
  const float* W      = (const float*)d_in[1];   // [128, 128] f32
  const int*   gidx   = (const int*)d_in[2];     // [E] int
  const int*   seg    = (const int*)d_in[3];     // [E] int, sorted
  float* out = (float*)d_out;                    // [N_OUT, 128] f32

  int*   offs = (int*)d_ws;                          // [N_OUT+1]
  float* g    = (float*)((char*)d_ws + OFFS_BYTES);  // [N_OUT, 128] f32

  const int n_edges = in_sizes[2];

  build_offs<<<(n_edges + 255) / 256, 256, 0, stream>>>(seg, offs, n_edges, NUM_OUT);
  seg_gather_sum<<<NUM_OUT / 2, 128, 0, stream>>>(values, gidx, offs, g, n_edges);
  gemm_tanh<<<(NUM_OUT + 63) / 64, 256, 0, stream>>>(g, W, out, NUM_OUT);
}

// Round 8
// 183.026 us; speedup vs baseline: 1.3669x; 1.1518x over previous
//
#include <hip/hip_runtime.h>

#define DIM 128
#define NUM_OUT 100000
#define OFFS_BYTES (((4 * (NUM_OUT + 1)) + 511) / 512 * 512)

typedef float v2f __attribute__((ext_vector_type(2)));
typedef float v4f __attribute__((ext_vector_type(4)));

__device__ __forceinline__ float fast_tanh(float x) {
  const float xc = fminf(fmaxf(x, -15.f), 15.f);
  const float t = __expf(2.f * xc);
  return __fdividef(t - 1.f, t + 1.f);
}

// Kernel 0: segment boundaries. offs[s] = first edge e with seg[e] >= s.
__global__ __launch_bounds__(256) void build_offs(
    const int* __restrict__ seg, int* __restrict__ offs, int n_edges, int n_out) {
  const int e = blockIdx.x * 256 + threadIdx.x;
  if (e >= n_edges) return;
  const int se = seg[e];
  const int sp = (e == 0) ? -1 : seg[e - 1];
  for (int s = sp + 1; s <= se; ++s) offs[s] = e;
  if (e == n_edges - 1) {
    for (int s = se + 1; s <= n_out; ++s) offs[s] = n_edges;
  }
}

// Kernel 1: per-segment gather+sum (proven R3 form, ~128 us: at the
// random-512B-gather fabric ceiling, ~6.8 TB/s delivered).
__global__ __launch_bounds__(128) void seg_gather_sum(
    const float* __restrict__ values,
    const int* __restrict__ gidx,
    const int* __restrict__ offs,
    float* __restrict__ g,
    int n_edges) {
  const int s = blockIdx.x * 2 + (threadIdx.x >> 6);
  const int t = threadIdx.x & 63;

  const int e0 = __builtin_amdgcn_readfirstlane(offs[s]);
  const int e1 = __builtin_amdgcn_readfirstlane(offs[s + 1]);
  const int len = e1 - e0;

  const v2f* __restrict__ v2 = (const v2f*)values;
  float accx = 0.f, accy = 0.f;

  for (int base = 0; base < len; base += 64) {
    const int my = gidx[min(e0 + base + t, n_edges - 1)];
    const int n = min(64, len - base);
    int k = 0;
    for (; k + 8 <= n; k += 8) {
      int r0 = __builtin_amdgcn_readlane(my, k + 0);
      int r1 = __builtin_amdgcn_readlane(my, k + 1);
      int r2 = __builtin_amdgcn_readlane(my, k + 2);
      int r3 = __builtin_amdgcn_readlane(my, k + 3);
      int r4 = __builtin_amdgcn_readlane(my, k + 4);
      int r5 = __builtin_amdgcn_readlane(my, k + 5);
      int r6 = __builtin_amdgcn_readlane(my, k + 6);
      int r7 = __builtin_amdgcn_readlane(my, k + 7);
      const v2f a0 = v2[(size_t)r0 * (DIM / 2) + t];
      const v2f a1 = v2[(size_t)r1 * (DIM / 2) + t];
      const v2f a2 = v2[(size_t)r2 * (DIM / 2) + t];
      const v2f a3 = v2[(size_t)r3 * (DIM / 2) + t];
      const v2f a4 = v2[(size_t)r4 * (DIM / 2) + t];
      const v2f a5 = v2[(size_t)r5 * (DIM / 2) + t];
      const v2f a6 = v2[(size_t)r6 * (DIM / 2) + t];
      const v2f a7 = v2[(size_t)r7 * (DIM / 2) + t];
      accx += a0.x + a1.x + a2.x + a3.x + a4.x + a5.x + a6.x + a7.x;
      accy += a0.y + a1.y + a2.y + a3.y + a4.y + a5.y + a6.y + a7.y;
    }
    if (k < n) {
      const int nm1 = n - 1;
#pragma unroll
      for (int j = 0; j < 7; j += 4) {
        if (k + j < n) {
          int q0 = __builtin_amdgcn_readlane(my, min(k + j + 0, nm1));
          int q1 = __builtin_amdgcn_readlane(my, min(k + j + 1, nm1));
          int q2 = __builtin_amdgcn_readlane(my, min(k + j + 2, nm1));
          int q3 = __builtin_amdgcn_readlane(my, min(k + j + 3, nm1));
          const float m1 = (k + j + 1 < n) ? 1.f : 0.f;
          const float m2 = (k + j + 2 < n) ? 1.f : 0.f;
          const float m3 = (k + j + 3 < n) ? 1.f : 0.f;
          const v2f b0 = v2[(size_t)q0 * (DIM / 2) + t];
          const v2f b1 = v2[(size_t)q1 * (DIM / 2) + t];
          const v2f b2 = v2[(size_t)q2 * (DIM / 2) + t];
          const v2f b3 = v2[(size_t)q3 * (DIM / 2) + t];
          accx += b0.x + m1 * b1.x + m2 * b2.x + m3 * b3.x;
          accy += b0.y + m1 * b1.y + m2 * b2.y + m3 * b3.y;
        }
      }
    }
  }

  v2f r;
  r.x = accx;
  r.y = accy;
  ((v2f*)g)[(size_t)s * (DIM / 2) + t] = r;
}

// Kernel 2: out = tanh(g @ W). 256 threads, 64 rows/block.
// g-block staged in LDS (32 KB, coalesced); d-loop reads g via low-latency
// ds_read broadcast + 4 W v4f loads (L2-hot) per 128 FMAs -> VALU-bound.
__global__ __launch_bounds__(256) void gemm_tanh(
    const float* __restrict__ g,
    const float* __restrict__ W,
    float* __restrict__ out,
    int n_rows) {
  __shared__ float gs[64 * DIM];  // 32 KB

  const int row0 = blockIdx.x * 64;

  // stage 64 rows coalesced: 256 threads x 8 v4f each
  {
    const int base_row = row0;
    for (int i = threadIdx.x; i < 64 * (DIM / 4); i += 256) {
      const int r = i >> 5;          // /32 v4f per row
      const int c = (i & 31);        // v4f index within row
      int rr = base_row + r;
      rr = rr < n_rows ? rr : n_rows - 1;
      ((v4f*)gs)[i] = *((const v4f*)(g + (size_t)rr * DIM) + c);
    }
  }
  __syncthreads();

  const int lane = threadIdx.x & 63;
  const int wv = threadIdx.x >> 6;   // 0..3
  const int h = lane >> 5;           // 0..1
  const int tx = lane & 31;          // 0..31
  const int f = tx * 4;              // output col base
  const int r0 = blockIdx.x * 64 + wv * 16 + h * 8;
  const int rloc = wv * 16 + h * 8;  // row offset within LDS tile

  float acc[8][4] = {};
#pragma unroll 1
  for (int d = 0; d < DIM; d += 4) {
    const v4f w0 = *(const v4f*)(W + (d + 0) * DIM + f);
    const v4f w1 = *(const v4f*)(W + (d + 1) * DIM + f);
    const v4f w2 = *(const v4f*)(W + (d + 2) * DIM + f);
    const v4f w3 = *(const v4f*)(W + (d + 3) * DIM + f);
#pragma unroll
    for (int r = 0; r < 8; ++r) {
      const v4f gv = *(const v4f*)(gs + (rloc + r) * DIM + d);
      acc[r][0] = fmaf(gv.x, w0.x, acc[r][0]);
      acc[r][1] = fmaf(gv.x, w0.y, acc[r][1]);
      acc[r][2] = fmaf(gv.x, w0.z, acc[r][2]);
      acc[r][3] = fmaf(gv.x, w0.w, acc[r][3]);
      acc[r][0] = fmaf(gv.y, w1.x, acc[r][0]);
      acc[r][1] = fmaf(gv.y, w1.y, acc[r][1]);
      acc[r][2] = fmaf(gv.y, w1.z, acc[r][2]);
      acc[r][3] = fmaf(gv.y, w1.w, acc[r][3]);
      acc[r][0] = fmaf(gv.z, w2.x, acc[r][0]);
      acc[r][1] = fmaf(gv.z, w2.y, acc[r][1]);
      acc[r][2] = fmaf(gv.z, w2.z, acc[r][2]);
      acc[r][3] = fmaf(gv.z, w2.w, acc[r][3]);
      acc[r][0] = fmaf(gv.w, w3.x, acc[r][0]);
      acc[r][1] = fmaf(gv.w, w3.y, acc[r][1]);
      acc[r][2] = fmaf(gv.w, w3.z, acc[r][2]);
      acc[r][3] = fmaf(gv.w, w3.w, acc[r][3]);
    }
  }

#pragma unroll
  for (int r = 0; r < 8; ++r) {
    const int rr = r0 + r;
    if (rr < n_rows) {
      v4f o;
      o.x = fast_tanh(acc[r][0]);
      o.y = fast_tanh(acc[r][1]);
      o.z = fast_tanh(acc[r][2]);
      o.w = fast_tanh(acc[r][3]);
      *(v4f*)(out + (size_t)rr * DIM + f) = o;
    }
  }
}

extern "C" void kernel_launch(void* const* d_in, const int* in_sizes, int n_in,
                              void* d_out, int out_size, void* d_ws, size_t ws_size,
                              hipStream_t stream) {
  const float* values = (const float*)d_in[0];   // [N_SRC, 128] f32
  const float* W      = (const float*)d_in[1];   // [128, 128] f32
  const int*   gidx   = (const int*)d_in[2];     // [E] int
  const int*   seg    = (const int*)d_in[3];     // [E] int, sorted
  float* out = (float*)d_out;                    // [N_OUT, 128] f32

  int*   offs = (int*)d_ws;                          // [N_OUT+1]
  float* g    = (float*)((char*)d_ws + OFFS_BYTES);  // [N_OUT, 128] f32

  const int n_edges = in_sizes[2];

  build_offs<<<(n_edges + 255) / 256, 256, 0, stream>>>(seg, offs, n_edges, NUM_OUT);
  seg_gather_sum<<<NUM_OUT / 2, 128, 0, stream>>>(values, gidx, offs, g, n_edges);
  gemm_tanh<<<(NUM_OUT + 63) / 64, 256, 0, stream>>>(g, W, out, NUM_OUT);
}

// Round 9
// 161.850 us; speedup vs baseline: 1.5458x; 1.1308x over previous
//
#include <hip/hip_runtime.h>

#define DIM 128
#define NUM_OUT 100000

typedef float v2f __attribute__((ext_vector_type(2)));
typedef float v4f __attribute__((ext_vector_type(4)));

__device__ __forceinline__ float fast_tanh(float x) {
  const float xc = fminf(fmaxf(x, -15.f), 15.f);
  const float t = __expf(2.f * xc);
  return __fdividef(t - 1.f, t + 1.f);
}

// Kernel 0: segment boundaries. offs[s] = first edge e with seg[e] >= s.
__global__ __launch_bounds__(256) void build_offs(
    const int* __restrict__ seg, int* __restrict__ offs, int n_edges, int n_out) {
  const int e = blockIdx.x * 256 + threadIdx.x;
  if (e >= n_edges) return;
  const int se = seg[e];
  const int sp = (e == 0) ? -1 : seg[e - 1];
  for (int s = sp + 1; s <= se; ++s) offs[s] = e;
  if (e == n_edges - 1) {
    for (int s = se + 1; s <= n_out; ++s) offs[s] = n_edges;
  }
}

// Fused kernel: block = 256 threads = 4 waves, 64 segments.
// Phase 1 (gather): wave w computes segment sums for its 16 segments
// (R3-proven 8-wide SGPR-broadcast gather) directly into the LDS tile.
// Phase 2 (GEMM): R8-proven LDS-fed register-tiled y = gs @ W, out = tanh(y).
// g never touches HBM; GEMM VALU hides under the fabric-bound gather.
__global__ __launch_bounds__(256) void fused_seg_gemm(
    const float* __restrict__ values,
    const int* __restrict__ gidx,
    const int* __restrict__ offs,
    const float* __restrict__ W,
    float* __restrict__ out,
    int n_edges) {
  __shared__ float gs[64 * DIM];  // 32 KB

  const int t = threadIdx.x & 63;
  const int w = threadIdx.x >> 6;  // 0..3
  const int row0 = blockIdx.x * 64;
  const int s0 = row0 + w * 16;

  // one coalesced load: boundaries offs[s0 .. s0+16] in lanes 0..16
  const int offv = offs[min(s0 + min(t, 16), NUM_OUT)];

  const v2f* __restrict__ v2 = (const v2f*)values;

#pragma unroll 1
  for (int i = 0; i < 16; ++i) {
    const int s = s0 + i;
    float accx = 0.f, accy = 0.f;
    if (s < NUM_OUT) {
      const int e0 = __builtin_amdgcn_readlane(offv, i);
      const int e1 = __builtin_amdgcn_readlane(offv, i + 1);
      const int len = e1 - e0;
#pragma unroll 1
      for (int base = 0; base < len; base += 64) {
        const int my = gidx[min(e0 + base + t, n_edges - 1)];
        const int n = min(64, len - base);
        int k = 0;
        for (; k + 8 <= n; k += 8) {
          int r0 = __builtin_amdgcn_readlane(my, k + 0);
          int r1 = __builtin_amdgcn_readlane(my, k + 1);
          int r2 = __builtin_amdgcn_readlane(my, k + 2);
          int r3 = __builtin_amdgcn_readlane(my, k + 3);
          int r4 = __builtin_amdgcn_readlane(my, k + 4);
          int r5 = __builtin_amdgcn_readlane(my, k + 5);
          int r6 = __builtin_amdgcn_readlane(my, k + 6);
          int r7 = __builtin_amdgcn_readlane(my, k + 7);
          const v2f a0 = v2[(size_t)r0 * (DIM / 2) + t];
          const v2f a1 = v2[(size_t)r1 * (DIM / 2) + t];
          const v2f a2 = v2[(size_t)r2 * (DIM / 2) + t];
          const v2f a3 = v2[(size_t)r3 * (DIM / 2) + t];
          const v2f a4 = v2[(size_t)r4 * (DIM / 2) + t];
          const v2f a5 = v2[(size_t)r5 * (DIM / 2) + t];
          const v2f a6 = v2[(size_t)r6 * (DIM / 2) + t];
          const v2f a7 = v2[(size_t)r7 * (DIM / 2) + t];
          accx += a0.x + a1.x + a2.x + a3.x + a4.x + a5.x + a6.x + a7.x;
          accy += a0.y + a1.y + a2.y + a3.y + a4.y + a5.y + a6.y + a7.y;
        }
        if (k < n) {
          const int nm1 = n - 1;
#pragma unroll
          for (int j = 0; j < 7; j += 4) {
            if (k + j < n) {
              int q0 = __builtin_amdgcn_readlane(my, min(k + j + 0, nm1));
              int q1 = __builtin_amdgcn_readlane(my, min(k + j + 1, nm1));
              int q2 = __builtin_amdgcn_readlane(my, min(k + j + 2, nm1));
              int q3 = __builtin_amdgcn_readlane(my, min(k + j + 3, nm1));
              const float m1 = (k + j + 1 < n) ? 1.f : 0.f;
              const float m2 = (k + j + 2 < n) ? 1.f : 0.f;
              const float m3 = (k + j + 3 < n) ? 1.f : 0.f;
              const v2f b0 = v2[(size_t)q0 * (DIM / 2) + t];
              const v2f b1 = v2[(size_t)q1 * (DIM / 2) + t];
              const v2f b2 = v2[(size_t)q2 * (DIM / 2) + t];
              const v2f b3 = v2[(size_t)q3 * (DIM / 2) + t];
              accx += b0.x + m1 * b1.x + m2 * b2.x + m3 * b3.x;
              accy += b0.y + m1 * b1.y + m2 * b2.y + m3 * b3.y;
            }
          }
        }
      }
    }
    v2f r;
    r.x = accx;
    r.y = accy;
    ((v2f*)gs)[(size_t)(w * 16 + i) * (DIM / 2) + t] = r;
  }

  __syncthreads();

  // Phase 2: GEMM + tanh (R8-proven form)
  const int lane = threadIdx.x & 63;
  const int h = lane >> 5;           // 0..1
  const int tx = lane & 31;          // 0..31
  const int f = tx * 4;              // output col base
  const int r0g = row0 + w * 16 + h * 8;
  const int rloc = w * 16 + h * 8;   // row offset within LDS tile

  float acc[8][4] = {};
#pragma unroll 1
  for (int d = 0; d < DIM; d += 4) {
    const v4f w0 = *(const v4f*)(W + (d + 0) * DIM + f);
    const v4f w1 = *(const v4f*)(W + (d + 1) * DIM + f);
    const v4f w2 = *(const v4f*)(W + (d + 2) * DIM + f);
    const v4f w3 = *(const v4f*)(W + (d + 3) * DIM + f);
#pragma unroll
    for (int r = 0; r < 8; ++r) {
      const v4f gv = *(const v4f*)(gs + (rloc + r) * DIM + d);
      acc[r][0] = fmaf(gv.x, w0.x, acc[r][0]);
      acc[r][1] = fmaf(gv.x, w0.y, acc[r][1]);
      acc[r][2] = fmaf(gv.x, w0.z, acc[r][2]);
      acc[r][3] = fmaf(gv.x, w0.w, acc[r][3]);
      acc[r][0] = fmaf(gv.y, w1.x, acc[r][0]);
      acc[r][1] = fmaf(gv.y, w1.y, acc[r][1]);
      acc[r][2] = fmaf(gv.y, w1.z, acc[r][2]);
      acc[r][3] = fmaf(gv.y, w1.w, acc[r][3]);
      acc[r][0] = fmaf(gv.z, w2.x, acc[r][0]);
      acc[r][1] = fmaf(gv.z, w2.y, acc[r][1]);
      acc[r][2] = fmaf(gv.z, w2.z, acc[r][2]);
      acc[r][3] = fmaf(gv.z, w2.w, acc[r][3]);
      acc[r][0] = fmaf(gv.w, w3.x, acc[r][0]);
      acc[r][1] = fmaf(gv.w, w3.y, acc[r][1]);
      acc[r][2] = fmaf(gv.w, w3.z, acc[r][2]);
      acc[r][3] = fmaf(gv.w, w3.w, acc[r][3]);
    }
  }

#pragma unroll
  for (int r = 0; r < 8; ++r) {
    const int rr = r0g + r;
    if (rr < NUM_OUT) {
      v4f o;
      o.x = fast_tanh(acc[r][0]);
      o.y = fast_tanh(acc[r][1]);
      o.z = fast_tanh(acc[r][2]);
      o.w = fast_tanh(acc[r][3]);
      *(v4f*)(out + (size_t)rr * DIM + f) = o;
    }
  }
}

extern "C" void kernel_launch(void* const* d_in, const int* in_sizes, int n_in,
                              void* d_out, int out_size, void* d_ws, size_t ws_size,
                              hipStream_t stream) {
  const float* values = (const float*)d_in[0];   // [N_SRC, 128] f32
  const float* W      = (const float*)d_in[1];   // [128, 128] f32
  const int*   gidx   = (const int*)d_in[2];     // [E] int
  const int*   seg    = (const int*)d_in[3];     // [E] int, sorted
  float* out = (float*)d_out;                    // [N_OUT, 128] f32

  int* offs = (int*)d_ws;                        // [N_OUT+1]

  const int n_edges = in_sizes[2];

  build_offs<<<(n_edges + 255) / 256, 256, 0, stream>>>(seg, offs, n_edges, NUM_OUT);
  fused_seg_gemm<<<(NUM_OUT + 63) / 64, 256, 0, stream>>>(values, gidx, offs, W, out, n_edges);
}

// Round 10
// 161.148 us; speedup vs baseline: 1.5525x; 1.0044x over previous
//
#include <hip/hip_runtime.h>

#define DIM 128
#define NUM_OUT 100000

typedef float v2f __attribute__((ext_vector_type(2)));
typedef float v4f __attribute__((ext_vector_type(4)));

__device__ __forceinline__ float fast_tanh(float x) {
  const float xc = fminf(fmaxf(x, -15.f), 15.f);
  const float t = __expf(2.f * xc);
  return __fdividef(t - 1.f, t + 1.f);
}

// Kernel 0: segment boundaries. offs[s] = first edge e with seg[e] >= s.
__global__ __launch_bounds__(256) void build_offs(
    const int* __restrict__ seg, int* __restrict__ offs, int n_edges, int n_out) {
  const int e = blockIdx.x * 256 + threadIdx.x;
  if (e >= n_edges) return;
  const int se = seg[e];
  const int sp = (e == 0) ? -1 : seg[e - 1];
  for (int s = sp + 1; s <= se; ++s) offs[s] = e;
  if (e == n_edges - 1) {
    for (int s = se + 1; s <= n_out; ++s) offs[s] = n_edges;
  }
}

// Fused kernel: block = 512 threads = 8 waves, 64 segments (8 per wave).
// Phase 1: R3-proven 8-wide SGPR-broadcast gather into the LDS tile.
// Phase 2: LDS-fed register-tiled y = gs @ W, out = tanh(y), 4x4 per thread.
// 4 blocks/CU (32 waves) co-resident -> gather memory + GEMM VALU overlap.
__global__ __launch_bounds__(512, 8) void fused_seg_gemm(
    const float* __restrict__ values,
    const int* __restrict__ gidx,
    const int* __restrict__ offs,
    const float* __restrict__ W,
    float* __restrict__ out,
    int n_edges) {
  __shared__ float gs[64 * DIM];  // 32 KB

  const int t = threadIdx.x & 63;
  const int w = threadIdx.x >> 6;  // 0..7
  const int row0 = blockIdx.x * 64;
  const int s0 = row0 + w * 8;

  // one coalesced load: boundaries offs[s0 .. s0+8] in lanes 0..8
  const int offv = offs[min(s0 + min(t, 8), NUM_OUT)];

  const v2f* __restrict__ v2 = (const v2f*)values;

#pragma unroll 1
  for (int i = 0; i < 8; ++i) {
    const int s = s0 + i;
    float accx = 0.f, accy = 0.f;
    if (s < NUM_OUT) {
      const int e0 = __builtin_amdgcn_readlane(offv, i);
      const int e1 = __builtin_amdgcn_readlane(offv, i + 1);
      const int len = e1 - e0;
#pragma unroll 1
      for (int base = 0; base < len; base += 64) {
        const int my = gidx[min(e0 + base + t, n_edges - 1)];
        const int n = min(64, len - base);
        int k = 0;
        for (; k + 8 <= n; k += 8) {
          int r0 = __builtin_amdgcn_readlane(my, k + 0);
          int r1 = __builtin_amdgcn_readlane(my, k + 1);
          int r2 = __builtin_amdgcn_readlane(my, k + 2);
          int r3 = __builtin_amdgcn_readlane(my, k + 3);
          int r4 = __builtin_amdgcn_readlane(my, k + 4);
          int r5 = __builtin_amdgcn_readlane(my, k + 5);
          int r6 = __builtin_amdgcn_readlane(my, k + 6);
          int r7 = __builtin_amdgcn_readlane(my, k + 7);
          const v2f a0 = v2[(size_t)r0 * (DIM / 2) + t];
          const v2f a1 = v2[(size_t)r1 * (DIM / 2) + t];
          const v2f a2 = v2[(size_t)r2 * (DIM / 2) + t];
          const v2f a3 = v2[(size_t)r3 * (DIM / 2) + t];
          const v2f a4 = v2[(size_t)r4 * (DIM / 2) + t];
          const v2f a5 = v2[(size_t)r5 * (DIM / 2) + t];
          const v2f a6 = v2[(size_t)r6 * (DIM / 2) + t];
          const v2f a7 = v2[(size_t)r7 * (DIM / 2) + t];
          accx += a0.x + a1.x + a2.x + a3.x + a4.x + a5.x + a6.x + a7.x;
          accy += a0.y + a1.y + a2.y + a3.y + a4.y + a5.y + a6.y + a7.y;
        }
        if (k < n) {
          const int nm1 = n - 1;
#pragma unroll
          for (int j = 0; j < 7; j += 4) {
            if (k + j < n) {
              int q0 = __builtin_amdgcn_readlane(my, min(k + j + 0, nm1));
              int q1 = __builtin_amdgcn_readlane(my, min(k + j + 1, nm1));
              int q2 = __builtin_amdgcn_readlane(my, min(k + j + 2, nm1));
              int q3 = __builtin_amdgcn_readlane(my, min(k + j + 3, nm1));
              const float m1 = (k + j + 1 < n) ? 1.f : 0.f;
              const float m2 = (k + j + 2 < n) ? 1.f : 0.f;
              const float m3 = (k + j + 3 < n) ? 1.f : 0.f;
              const v2f b0 = v2[(size_t)q0 * (DIM / 2) + t];
              const v2f b1 = v2[(size_t)q1 * (DIM / 2) + t];
              const v2f b2 = v2[(size_t)q2 * (DIM / 2) + t];
              const v2f b3 = v2[(size_t)q3 * (DIM / 2) + t];
              accx += b0.x + m1 * b1.x + m2 * b2.x + m3 * b3.x;
              accy += b0.y + m1 * b1.y + m2 * b2.y + m3 * b3.y;
            }
          }
        }
      }
    }
    v2f r;
    r.x = accx;
    r.y = accy;
    ((v2f*)gs)[(size_t)(w * 8 + i) * (DIM / 2) + t] = r;
  }

  __syncthreads();

  // Phase 2: GEMM + tanh. Wave w -> rows [8w, 8w+8); thread tile 4x4.
  const int h = t >> 5;              // 0..1
  const int tx = t & 31;             // 0..31
  const int f = tx * 4;              // output col base
  const int rloc = w * 8 + h * 4;    // row offset within LDS tile
  const int r0g = row0 + rloc;

  float acc[4][4] = {};
#pragma unroll 1
  for (int d = 0; d < DIM; d += 4) {
    const v4f w0 = *(const v4f*)(W + (d + 0) * DIM + f);
    const v4f w1 = *(const v4f*)(W + (d + 1) * DIM + f);
    const v4f w2 = *(const v4f*)(W + (d + 2) * DIM + f);
    const v4f w3 = *(const v4f*)(W + (d + 3) * DIM + f);
#pragma unroll
    for (int r = 0; r < 4; ++r) {
      const v4f gv = *(const v4f*)(gs + (rloc + r) * DIM + d);
      acc[r][0] = fmaf(gv.x, w0.x, acc[r][0]);
      acc[r][1] = fmaf(gv.x, w0.y, acc[r][1]);
      acc[r][2] = fmaf(gv.x, w0.z, acc[r][2]);
      acc[r][3] = fmaf(gv.x, w0.w, acc[r][3]);
      acc[r][0] = fmaf(gv.y, w1.x, acc[r][0]);
      acc[r][1] = fmaf(gv.y, w1.y, acc[r][1]);
      acc[r][2] = fmaf(gv.y, w1.z, acc[r][2]);
      acc[r][3] = fmaf(gv.y, w1.w, acc[r][3]);
      acc[r][0] = fmaf(gv.z, w2.x, acc[r][0]);
      acc[r][1] = fmaf(gv.z, w2.y, acc[r][1]);
      acc[r][2] = fmaf(gv.z, w2.z, acc[r][2]);
      acc[r][3] = fmaf(gv.z, w2.w, acc[r][3]);
      acc[r][0] = fmaf(gv.w, w3.x, acc[r][0]);
      acc[r][1] = fmaf(gv.w, w3.y, acc[r][1]);
      acc[r][2] = fmaf(gv.w, w3.z, acc[r][2]);
      acc[r][3] = fmaf(gv.w, w3.w, acc[r][3]);
    }
  }

#pragma unroll
  for (int r = 0; r < 4; ++r) {
    const int rr = r0g + r;
    if (rr < NUM_OUT) {
      v4f o;
      o.x = fast_tanh(acc[r][0]);
      o.y = fast_tanh(acc[r][1]);
      o.z = fast_tanh(acc[r][2]);
      o.w = fast_tanh(acc[r][3]);
      *(v4f*)(out + (size_t)rr * DIM + f) = o;
    }
  }
}

extern "C" void kernel_launch(void* const* d_in, const int* in_sizes, int n_in,
                              void* d_out, int out_size, void* d_ws, size_t ws_size,
                              hipStream_t stream) {
  const float* values = (const float*)d_in[0];   // [N_SRC, 128] f32
  const float* W      = (const float*)d_in[1];   // [128, 128] f32
  const int*   gidx   = (const int*)d_in[2];     // [E] int
  const int*   seg    = (const int*)d_in[3];     // [E] int, sorted
  float* out = (float*)d_out;                    // [N_OUT, 128] f32

  int* offs = (int*)d_ws;                        // [N_OUT+1]

  const int n_edges = in_sizes[2];

  build_offs<<<(n_edges + 255) / 256, 256, 0, stream>>>(seg, offs, n_edges, NUM_OUT);
  fused_seg_gemm<<<(NUM_OUT + 63) / 64, 512, 0, stream>>>(values, gidx, offs, W, out, n_edges);
}

// Round 11
// 160.766 us; speedup vs baseline: 1.5562x; 1.0024x over previous
//
#include <hip/hip_runtime.h>

#define DIM 128
#define NUM_OUT 100000

typedef float v2f __attribute__((ext_vector_type(2)));
typedef float v4f __attribute__((ext_vector_type(4)));

__device__ __forceinline__ float fast_tanh(float x) {
  const float xc = fminf(fmaxf(x, -15.f), 15.f);
  const float t = __expf(2.f * xc);
  return __fdividef(t - 1.f, t + 1.f);
}

// Kernel 0: segment boundaries. offs[s] = first edge e with seg[e] >= s.
__global__ __launch_bounds__(256) void build_offs(
    const int* __restrict__ seg, int* __restrict__ offs, int n_edges, int n_out) {
  const int e = blockIdx.x * 256 + threadIdx.x;
  if (e >= n_edges) return;
  const int se = seg[e];
  const int sp = (e == 0) ? -1 : seg[e - 1];
  for (int s = sp + 1; s <= se; ++s) offs[s] = e;
  if (e == n_edges - 1) {
    for (int s = se + 1; s <= n_out; ++s) offs[s] = n_edges;
  }
}

// Fused kernel: block = 512 threads = 8 waves, 64 segments (8 per wave).
// Each wave is fully self-contained: it gathers its 8 segments into its own
// LDS rows, then GEMMs those same rows. NO __syncthreads — wave w reads only
// LDS rows it wrote itself (intra-wave lgkmcnt ordering suffices). Waves
// drift out of phase, so gather (memory) and GEMM (VALU) overlap organically
// across the ~23 resident waves per CU.
__global__ __launch_bounds__(512, 8) void fused_seg_gemm(
    const float* __restrict__ values,
    const int* __restrict__ gidx,
    const int* __restrict__ offs,
    const float* __restrict__ W,
    float* __restrict__ out,
    int n_edges) {
  __shared__ float gs[64 * DIM];  // 32 KB

  const int t = threadIdx.x & 63;
  const int w = threadIdx.x >> 6;  // 0..7
  const int row0 = blockIdx.x * 64;
  const int s0 = row0 + w * 8;

  // one coalesced load: boundaries offs[s0 .. s0+8] in lanes 0..8
  const int offv = offs[min(s0 + min(t, 8), NUM_OUT)];

  const v2f* __restrict__ v2 = (const v2f*)values;

#pragma unroll 1
  for (int i = 0; i < 8; ++i) {
    const int s = s0 + i;
    float accx = 0.f, accy = 0.f;
    if (s < NUM_OUT) {
      const int e0 = __builtin_amdgcn_readlane(offv, i);
      const int e1 = __builtin_amdgcn_readlane(offv, i + 1);
      const int len = e1 - e0;
#pragma unroll 1
      for (int base = 0; base < len; base += 64) {
        const int my = gidx[min(e0 + base + t, n_edges - 1)];
        const int n = min(64, len - base);
        int k = 0;
        for (; k + 8 <= n; k += 8) {
          int r0 = __builtin_amdgcn_readlane(my, k + 0);
          int r1 = __builtin_amdgcn_readlane(my, k + 1);
          int r2 = __builtin_amdgcn_readlane(my, k + 2);
          int r3 = __builtin_amdgcn_readlane(my, k + 3);
          int r4 = __builtin_amdgcn_readlane(my, k + 4);
          int r5 = __builtin_amdgcn_readlane(my, k + 5);
          int r6 = __builtin_amdgcn_readlane(my, k + 6);
          int r7 = __builtin_amdgcn_readlane(my, k + 7);
          const v2f a0 = v2[(size_t)r0 * (DIM / 2) + t];
          const v2f a1 = v2[(size_t)r1 * (DIM / 2) + t];
          const v2f a2 = v2[(size_t)r2 * (DIM / 2) + t];
          const v2f a3 = v2[(size_t)r3 * (DIM / 2) + t];
          const v2f a4 = v2[(size_t)r4 * (DIM / 2) + t];
          const v2f a5 = v2[(size_t)r5 * (DIM / 2) + t];
          const v2f a6 = v2[(size_t)r6 * (DIM / 2) + t];
          const v2f a7 = v2[(size_t)r7 * (DIM / 2) + t];
          accx += a0.x + a1.x + a2.x + a3.x + a4.x + a5.x + a6.x + a7.x;
          accy += a0.y + a1.y + a2.y + a3.y + a4.y + a5.y + a6.y + a7.y;
        }
        if (k < n) {
          const int nm1 = n - 1;
#pragma unroll
          for (int j = 0; j < 7; j += 4) {
            if (k + j < n) {
              int q0 = __builtin_amdgcn_readlane(my, min(k + j + 0, nm1));
              int q1 = __builtin_amdgcn_readlane(my, min(k + j + 1, nm1));
              int q2 = __builtin_amdgcn_readlane(my, min(k + j + 2, nm1));
              int q3 = __builtin_amdgcn_readlane(my, min(k + j + 3, nm1));
              const float m1 = (k + j + 1 < n) ? 1.f : 0.f;
              const float m2 = (k + j + 2 < n) ? 1.f : 0.f;
              const float m3 = (k + j + 3 < n) ? 1.f : 0.f;
              const v2f b0 = v2[(size_t)q0 * (DIM / 2) + t];
              const v2f b1 = v2[(size_t)q1 * (DIM / 2) + t];
              const v2f b2 = v2[(size_t)q2 * (DIM / 2) + t];
              const v2f b3 = v2[(size_t)q3 * (DIM / 2) + t];
              accx += b0.x + m1 * b1.x + m2 * b2.x + m3 * b3.x;
              accy += b0.y + m1 * b1.y + m2 * b2.y + m3 * b3.y;
            }
          }
        }
      }
    }
    v2f r;
    r.x = accx;
    r.y = accy;
    ((v2f*)gs)[(size_t)(w * 8 + i) * (DIM / 2) + t] = r;
  }

  // NO __syncthreads: wave w reads only rows [8w, 8w+8) which it wrote.

  // Phase 2: GEMM + tanh. Wave w -> rows [8w, 8w+8); thread tile 4x4.
  const int h = t >> 5;              // 0..1
  const int tx = t & 31;             // 0..31
  const int f = tx * 4;              // output col base
  const int rloc = w * 8 + h * 4;    // row offset within LDS tile
  const int r0g = row0 + rloc;

  float acc[4][4] = {};
#pragma unroll 1
  for (int d = 0; d < DIM; d += 4) {
    const v4f w0 = *(const v4f*)(W + (d + 0) * DIM + f);
    const v4f w1 = *(const v4f*)(W + (d + 1) * DIM + f);
    const v4f w2 = *(const v4f*)(W + (d + 2) * DIM + f);
    const v4f w3 = *(const v4f*)(W + (d + 3) * DIM + f);
#pragma unroll
    for (int r = 0; r < 4; ++r) {
      const v4f gv = *(const v4f*)(gs + (rloc + r) * DIM + d);
      acc[r][0] = fmaf(gv.x, w0.x, acc[r][0]);
      acc[r][1] = fmaf(gv.x, w0.y, acc[r][1]);
      acc[r][2] = fmaf(gv.x, w0.z, acc[r][2]);
      acc[r][3] = fmaf(gv.x, w0.w, acc[r][3]);
      acc[r][0] = fmaf(gv.y, w1.x, acc[r][0]);
      acc[r][1] = fmaf(gv.y, w1.y, acc[r][1]);
      acc[r][2] = fmaf(gv.y, w1.z, acc[r][2]);
      acc[r][3] = fmaf(gv.y, w1.w, acc[r][3]);
      acc[r][0] = fmaf(gv.z, w2.x, acc[r][0]);
      acc[r][1] = fmaf(gv.z, w2.y, acc[r][1]);
      acc[r][2] = fmaf(gv.z, w2.z, acc[r][2]);
      acc[r][3] = fmaf(gv.z, w2.w, acc[r][3]);
      acc[r][0] = fmaf(gv.w, w3.x, acc[r][0]);
      acc[r][1] = fmaf(gv.w, w3.y, acc[r][1]);
      acc[r][2] = fmaf(gv.w, w3.z, acc[r][2]);
      acc[r][3] = fmaf(gv.w, w3.w, acc[r][3]);
    }
  }

#pragma unroll
  for (int r = 0; r < 4; ++r) {
    const int rr = r0g + r;
    if (rr < NUM_OUT) {
      v4f o;
      o.x = fast_tanh(acc[r][0]);
      o.y = fast_tanh(acc[r][1]);
      o.z = fast_tanh(acc[r][2]);
      o.w = fast_tanh(acc[r][3]);
      *(v4f*)(out + (size_t)rr * DIM + f) = o;
    }
  }
}

extern "C" void kernel_launch(void* const* d_in, const int* in_sizes, int n_in,
                              void* d_out, int out_size, void* d_ws, size_t ws_size,
                              hipStream_t stream) {
  const float* values = (const float*)d_in[0];   // [N_SRC, 128] f32
  const float* W      = (const float*)d_in[1];   // [128, 128] f32
  const int*   gidx   = (const int*)d_in[2];     // [E] int
  const int*   seg    = (const int*)d_in[3];     // [E] int, sorted
  float* out = (float*)d_out;                    // [N_OUT, 128] f32

  int* offs = (int*)d_ws;                        // [N_OUT+1]

  const int n_edges = in_sizes[2];

  build_offs<<<(n_edges + 255) / 256, 256, 0, stream>>>(seg, offs, n_edges, NUM_OUT);
  fused_seg_gemm<<<(NUM_OUT + 63) / 64, 512, 0, stream>>>(values, gidx, offs, W, out, n_edges);
}